// Round 9
// baseline (80.155 us; speedup 1.0000x reference)
//
#include <hip/hip_runtime.h>

#define NUM_WIRES 4
#define NUM_LAYERS 2

// Packed-pair simulator: each thread simulates TWO batch elements (A,B),
// packed as the two halves of <2 x float> registers. A and B run the
// bit-identical real-arithmetic DAG, so every op is elementwise -> the
// backend can emit v_pk_fma_f32 (full-rate packed f32 on CDNA) with NO
// cross-half swizzles (the failure mode of the round-3 (re,im) packing).
// Gate constants stay scalar wave-uniform SGPRs (R4/R8-proven rfl path).
//
// ws layout (floats):
//  [ 0..15]  layer-0 per wire w: {A=cx*cz, B=cx*sz, C=sx*sz, D=sx*cz}
//  [16..23]  layer-1 RX per wire: {cos, sin}
//  [24..55]  layer-1 combined RZ diagonal: 16 x {dr, di}
//
// State layout: amp[i], bit3=wire0 ... bit0=wire3 (reference (B,2,2,2,2) order).

#define INV_4PI 0.07957747154594767f  // 0.5/(2*pi): sin(0.5x) = v_sin(x*INV_4PI)

typedef float v2 __attribute__((ext_vector_type(2)));

__global__ void gate_prep(const float* __restrict__ params, float* __restrict__ g) {
    const int t = threadIdx.x;
    if (t < 4) {
        const float p0 = params[t * 2 + 0];  // RZ
        const float p1 = params[t * 2 + 1];  // RX
        float cz, sz, cx, sx;
        __sincosf(0.5f * p0, &sz, &cz);
        __sincosf(0.5f * p1, &sx, &cx);
        g[t * 4 + 0] = cx * cz;
        g[t * 4 + 1] = cx * sz;
        g[t * 4 + 2] = sx * sz;
        g[t * 4 + 3] = sx * cz;
    } else if (t < 8) {
        const int w = t - 4;
        const float p1 = params[(NUM_WIRES + w) * 2 + 1];
        float cx, sx;
        __sincosf(0.5f * p1, &sx, &cx);
        g[16 + w * 2] = cx;
        g[17 + w * 2] = sx;
    } else if (t >= 16 && t < 32) {
        const int i = t - 16;
        float dr = 1.f, di = 0.f;
        for (int w = 0; w < NUM_WIRES; ++w) {
            const float p0 = params[(NUM_WIRES + w) * 2 + 0];
            float c, s;
            __sincosf(0.5f * p0, &s, &c);
            const float sg = ((i >> (3 - w)) & 1) ? s : -s;
            const float ndr = dr * c - di * sg;
            const float ndi = dr * sg + di * c;
            dr = ndr; di = ndi;
        }
        g[24 + i * 2] = dr;
        g[25 + i * 2] = di;
    }
}

__device__ __forceinline__ float rfl(float v) {
    return __int_as_float(__builtin_amdgcn_readfirstlane(__float_as_int(v)));
}

__device__ __forceinline__ v2 ef(v2 a, v2 b, v2 c) { return __builtin_elementwise_fma(a, b, c); }
__device__ __forceinline__ v2 sp(float x) { v2 r; r.x = x; r.y = x; return r; }

// (or,oi) = (ar,ai) * (br,bi), elementwise over the (A,B) pair
__device__ __forceinline__ void cmul(v2 ar, v2 ai, v2 br, v2 bi, v2& orr, v2& oi) {
    orr = ef(ar, br, -(ai * bi));
    oi  = ef(ar, bi,   ai * br);
}

template <int CM, int TM>
__device__ __forceinline__ void cnot(v2 zr[16], v2 zi[16]) {
#pragma unroll
    for (int i = 0; i < 16; ++i) {
        if ((i & CM) && !(i & TM)) {
            const int j = i | TM;
            v2 t;
            t = zr[i]; zr[i] = zr[j]; zr[j] = t;
            t = zi[i]; zi[i] = zi[j]; zi[j] = t;
        }
    }
}

__global__ __launch_bounds__(256) void qsim_kernel(const float* __restrict__ x,
                                                   const float* __restrict__ gf,
                                                   float* __restrict__ out, int batch) {
    const int tid = threadIdx.x;
    const int i0 = blockIdx.x * 512 + tid;
    const int i1 = i0 + 256;

    // 56 wave-uniform gate constants -> SGPRs
    float G[56];
#pragma unroll
    for (int k = 0; k < 14; ++k) {
        const float4 v = reinterpret_cast<const float4*>(gf)[k];
        G[4 * k + 0] = rfl(v.x);
        G[4 * k + 1] = rfl(v.y);
        G[4 * k + 2] = rfl(v.z);
        G[4 * k + 3] = rfl(v.w);
    }

    const float4 xa = (i0 < batch) ? reinterpret_cast<const float4*>(x)[i0]
                                   : make_float4(0.f, 0.f, 0.f, 0.f);
    const float4 xb = (i1 < batch) ? reinterpret_cast<const float4*>(x)[i1]
                                   : make_float4(0.f, 0.f, 0.f, 0.f);

    // Packed angles: half .x = element A, half .y = element B.
    v2 xs[4];
    xs[0].x = xa.x; xs[0].y = xb.x;
    xs[1].x = xa.y; xs[1].y = xb.y;
    xs[2].x = xa.z; xs[2].y = xb.z;
    xs[3].x = xa.w; xs[3].y = xb.w;

    // Layer-0: fused gate applied to each wire's RY(x)|0> = (c,s) factor.
    v2 fr[4][2], fi[4][2];
#pragma unroll
    for (int w = 0; w < 4; ++w) {
        const v2 r = xs[w] * sp(INV_4PI);
        v2 s, c;
        s.x = __builtin_amdgcn_sinf(r.x);
        s.y = __builtin_amdgcn_sinf(r.y);
        c.x = __builtin_amdgcn_cosf(r.x);
        c.y = __builtin_amdgcn_cosf(r.y);
        const float A = G[w * 4 + 0], B = G[w * 4 + 1];
        const float C = G[w * 4 + 2], D = G[w * 4 + 3];
        fr[w][0] = ef(sp(A), c, sp(C) * s);        // u00r*c + u01r*s
        fi[w][0] = ef(sp(-B), c, -(sp(D) * s));    // u00i*c + u01i*s
        fr[w][1] = ef(sp(A), s, -(sp(C) * c));     // u10r*c + u11r*s
        fi[w][1] = ef(sp(B), s, -(sp(D) * c));     // u10i*c + u11i*s
    }

    // Complex outer product: z = (f0 (x) f1) (x) (f2 (x) f3)
    v2 mr[4], mi[4], nr[4], ni[4];
#pragma unroll
    for (int p = 0; p < 2; ++p)
#pragma unroll
        for (int q = 0; q < 2; ++q) {
            cmul(fr[0][p], fi[0][p], fr[1][q], fi[1][q], mr[p * 2 + q], mi[p * 2 + q]);
            cmul(fr[2][p], fi[2][p], fr[3][q], fi[3][q], nr[p * 2 + q], ni[p * 2 + q]);
        }
    v2 zr[16], zi[16];
#pragma unroll
    for (int i = 0; i < 16; ++i)
        cmul(mr[i >> 2], mi[i >> 2], nr[i & 3], ni[i & 3], zr[i], zi[i]);

    // Layer-0 CNOT ring (free register permutation)
    cnot<8, 4>(zr, zi);
    cnot<4, 2>(zr, zi);
    cnot<2, 1>(zr, zi);
    cnot<1, 8>(zr, zi);

    // Layer-1 combined RZ diagonal
#pragma unroll
    for (int i = 0; i < 16; ++i) {
        const float dr = G[24 + i * 2], di = G[25 + i * 2];
        const v2 ar = zr[i], ai = zi[i];
        zr[i] = ef(sp(dr), ar, -(sp(di) * ai));
        zi[i] = ef(sp(dr), ai,   sp(di) * ar);
    }

    // Layer-1 RX per wire: new_a = c*a - i*s*b -> (c*ar + s*bi, c*ai - s*br)
#pragma unroll
    for (int w = 0; w < 4; ++w) {
        const v2 c = sp(G[16 + w * 2]), s = sp(G[17 + w * 2]);
        const int M = 8 >> w;
#pragma unroll
        for (int i = 0; i < 16; ++i) {
            if (!(i & M)) {
                const int j = i | M;
                const v2 ar = zr[i], ai = zi[i];
                const v2 br = zr[j], bi = zi[j];
                zr[i] = ef(c, ar,   s * bi);
                zi[i] = ef(c, ai, -(s * br));
                zr[j] = ef(c, br,   s * ai);
                zi[j] = ef(c, bi, -(s * ar));
            }
        }
    }

    // Layer-1 CNOT ring
    cnot<8, 4>(zr, zi);
    cnot<4, 2>(zr, zi);
    cnot<2, 1>(zr, zi);
    cnot<1, 8>(zr, zi);

    // Probabilities and <Z_w> via sum/difference tree (still packed)
    v2 p[16];
#pragma unroll
    for (int i = 0; i < 16; ++i) p[i] = ef(zr[i], zr[i], zi[i] * zi[i]);

    v2 d0[8], s1[8];
#pragma unroll
    for (int k = 0; k < 8; ++k) {
        d0[k] = p[2 * k] - p[2 * k + 1];
        s1[k] = p[2 * k] + p[2 * k + 1];
    }
    const v2 e3 = ((d0[0] + d0[1]) + (d0[2] + d0[3])) + ((d0[4] + d0[5]) + (d0[6] + d0[7]));
    const v2 e2 = ((s1[0] - s1[1]) + (s1[2] - s1[3])) + ((s1[4] - s1[5]) + (s1[6] - s1[7]));
    v2 s2[4];
#pragma unroll
    for (int k = 0; k < 4; ++k) s2[k] = s1[2 * k] + s1[2 * k + 1];
    const v2 e1 = (s2[0] - s2[1]) + (s2[2] - s2[3]);
    const v2 e0 = (s2[0] + s2[1]) - (s2[2] + s2[3]);

    // Unpack halves (free: halves are distinct VGPRs) and store coalesced.
    if (i0 < batch)
        reinterpret_cast<float4*>(out)[i0] = make_float4(e0.x, e1.x, e2.x, e3.x);
    if (i1 < batch)
        reinterpret_cast<float4*>(out)[i1] = make_float4(e0.y, e1.y, e2.y, e3.y);
}

extern "C" void kernel_launch(void* const* d_in, const int* in_sizes, int n_in,
                              void* d_out, int out_size, void* d_ws, size_t ws_size,
                              hipStream_t stream) {
    const float* x = (const float*)d_in[0];        // (B, 4) float32
    const float* params = (const float*)d_in[1];   // (2, 4, 2) float32
    float* out = (float*)d_out;                    // (B, 4) float32
    float* g = (float*)d_ws;                       // 56 floats of gate constants
    const int batch = in_sizes[0] / NUM_WIRES;

    gate_prep<<<1, 64, 0, stream>>>(params, g);
    const int blocks = (batch + 511) / 512;
    qsim_kernel<<<blocks, 256, 0, stream>>>(x, g, out, batch);
}

// Round 10
// 79.107 us; speedup vs baseline: 1.0132x; 1.0132x over previous
//
#include <hip/hip_runtime.h>

#define NUM_WIRES 4
#define NUM_LAYERS 2

// Packed-f16 pair simulator: each thread simulates TWO batch elements (A,B)
// packed as the two halves of half2 registers -> v_pk_fma_f16 (one 32-bit
// register per pair, unlike VOP3P-f32 which needs register pairs and killed
// round 9 with splat movs). Gate constants are stored half-replicated in a
// single uint each: one readfirstlane -> one SGPR -> legal VOP3P source with
// zero per-thread splat cost. Trig in f32 HW (v_sin/v_cos), ev tree in f32.
//
// ws layout (uints, each = (h<<16)|h of the f16 coefficient):
//  [ 0..15]  layer-0 per wire w: {A=cx*cz, B=cx*sz, C=sx*sz, D=sx*cz}
//  [16..23]  layer-1 RX per wire: {cos, sin}
//  [24..55]  layer-1 combined RZ diagonal: 16 x {dr, di}
//
// State layout: amp[i], bit3=wire0 ... bit0=wire3 (reference (B,2,2,2,2) order).

#define INV_4PI 0.07957747154594767f  // 0.5/(2*pi): sin(0.5x) = v_sin(x*INV_4PI)

typedef _Float16 h2 __attribute__((ext_vector_type(2)));

__device__ __forceinline__ unsigned int rep16(float v) {
    const _Float16 h = (_Float16)v;
    unsigned short hs;
    __builtin_memcpy(&hs, &h, 2);
    return ((unsigned int)hs << 16) | hs;
}

__global__ void gate_prep(const float* __restrict__ params, unsigned int* __restrict__ g) {
    const int t = threadIdx.x;
    if (t < 4) {
        const float p0 = params[t * 2 + 0];  // RZ
        const float p1 = params[t * 2 + 1];  // RX
        float cz, sz, cx, sx;
        __sincosf(0.5f * p0, &sz, &cz);
        __sincosf(0.5f * p1, &sx, &cx);
        g[t * 4 + 0] = rep16(cx * cz);
        g[t * 4 + 1] = rep16(cx * sz);
        g[t * 4 + 2] = rep16(sx * sz);
        g[t * 4 + 3] = rep16(sx * cz);
    } else if (t < 8) {
        const int w = t - 4;
        const float p1 = params[(NUM_WIRES + w) * 2 + 1];
        float cx, sx;
        __sincosf(0.5f * p1, &sx, &cx);
        g[16 + w * 2] = rep16(cx);
        g[17 + w * 2] = rep16(sx);
    } else if (t >= 16 && t < 32) {
        const int i = t - 16;
        float dr = 1.f, di = 0.f;
        for (int w = 0; w < NUM_WIRES; ++w) {
            const float p0 = params[(NUM_WIRES + w) * 2 + 0];
            float c, s;
            __sincosf(0.5f * p0, &s, &c);
            const float sg = ((i >> (3 - w)) & 1) ? s : -s;
            const float ndr = dr * c - di * sg;
            const float ndi = dr * sg + di * c;
            dr = ndr; di = ndi;
        }
        g[24 + i * 2] = rep16(dr);
        g[25 + i * 2] = rep16(di);
    }
}

__device__ __forceinline__ h2 ef(h2 a, h2 b, h2 c) { return __builtin_elementwise_fma(a, b, c); }

__device__ __forceinline__ h2 u2h(unsigned int u) {
    h2 r;
    __builtin_memcpy(&r, &u, 4);
    return r;
}

// (or,oi) = (ar,ai) * (br,bi), elementwise over the (A,B) pair
__device__ __forceinline__ void cmul(h2 ar, h2 ai, h2 br, h2 bi, h2& orr, h2& oi) {
    orr = ef(ar, br, -(ai * bi));
    oi  = ef(ar, bi,   ai * br);
}

template <int CM, int TM>
__device__ __forceinline__ void cnot(h2 zr[16], h2 zi[16]) {
#pragma unroll
    for (int i = 0; i < 16; ++i) {
        if ((i & CM) && !(i & TM)) {
            const int j = i | TM;
            h2 t;
            t = zr[i]; zr[i] = zr[j]; zr[j] = t;
            t = zi[i]; zi[i] = zi[j]; zi[j] = t;
        }
    }
}

__global__ __launch_bounds__(256) void qsim_kernel(const float* __restrict__ x,
                                                   const unsigned int* __restrict__ gu,
                                                   float* __restrict__ out, int batch) {
    const int tid = threadIdx.x;
    const int i0 = blockIdx.x * 512 + tid;
    const int i1 = i0 + 256;

    // 56 half-replicated gate constants -> SGPRs (one rfl each).
    h2 G[56];
#pragma unroll
    for (int k = 0; k < 14; ++k) {
        const uint4 v = reinterpret_cast<const uint4*>(gu)[k];
        G[4 * k + 0] = u2h((unsigned int)__builtin_amdgcn_readfirstlane((int)v.x));
        G[4 * k + 1] = u2h((unsigned int)__builtin_amdgcn_readfirstlane((int)v.y));
        G[4 * k + 2] = u2h((unsigned int)__builtin_amdgcn_readfirstlane((int)v.z));
        G[4 * k + 3] = u2h((unsigned int)__builtin_amdgcn_readfirstlane((int)v.w));
    }

    const float4 xa = (i0 < batch) ? reinterpret_cast<const float4*>(x)[i0]
                                   : make_float4(0.f, 0.f, 0.f, 0.f);
    const float4 xb = (i1 < batch) ? reinterpret_cast<const float4*>(x)[i1]
                                   : make_float4(0.f, 0.f, 0.f, 0.f);

    // Layer-0: fused gate on each wire's RY(x)|0> = (c,s) factor; trig in f32,
    // then pack (A,B) into half2.
    h2 fr[4][2], fi[4][2];
    {
        const float axs[4] = {xa.x, xa.y, xa.z, xa.w};
        const float bxs[4] = {xb.x, xb.y, xb.z, xb.w};
#pragma unroll
        for (int w = 0; w < 4; ++w) {
            const float rA = axs[w] * INV_4PI;
            const float rB = bxs[w] * INV_4PI;
            h2 s, c;
            s.x = (_Float16)__builtin_amdgcn_sinf(rA);
            s.y = (_Float16)__builtin_amdgcn_sinf(rB);
            c.x = (_Float16)__builtin_amdgcn_cosf(rA);
            c.y = (_Float16)__builtin_amdgcn_cosf(rB);
            const h2 A = G[w * 4 + 0], B = G[w * 4 + 1];
            const h2 C = G[w * 4 + 2], D = G[w * 4 + 3];
            fr[w][0] = ef(A, c, C * s);        // u00r*c + u01r*s
            fi[w][0] = ef(-B, c, -(D * s));    // u00i*c + u01i*s
            fr[w][1] = ef(A, s, -(C * c));     // u10r*c + u11r*s
            fi[w][1] = ef(B, s, -(D * c));     // u10i*c + u11i*s
        }
    }

    // Complex outer product: z = (f0 (x) f1) (x) (f2 (x) f3)
    h2 mr[4], mi[4], nr[4], ni[4];
#pragma unroll
    for (int p = 0; p < 2; ++p)
#pragma unroll
        for (int q = 0; q < 2; ++q) {
            cmul(fr[0][p], fi[0][p], fr[1][q], fi[1][q], mr[p * 2 + q], mi[p * 2 + q]);
            cmul(fr[2][p], fi[2][p], fr[3][q], fi[3][q], nr[p * 2 + q], ni[p * 2 + q]);
        }
    h2 zr[16], zi[16];
#pragma unroll
    for (int i = 0; i < 16; ++i)
        cmul(mr[i >> 2], mi[i >> 2], nr[i & 3], ni[i & 3], zr[i], zi[i]);

    // Layer-0 CNOT ring (free register permutation)
    cnot<8, 4>(zr, zi);
    cnot<4, 2>(zr, zi);
    cnot<2, 1>(zr, zi);
    cnot<1, 8>(zr, zi);

    // Layer-1 combined RZ diagonal
#pragma unroll
    for (int i = 0; i < 16; ++i) {
        const h2 dr = G[24 + i * 2], di = G[25 + i * 2];
        const h2 ar = zr[i], ai = zi[i];
        zr[i] = ef(dr, ar, -(di * ai));
        zi[i] = ef(dr, ai,   di * ar);
    }

    // Layer-1 RX per wire: new_a = c*a - i*s*b -> (c*ar + s*bi, c*ai - s*br)
#pragma unroll
    for (int w = 0; w < 4; ++w) {
        const h2 c = G[16 + w * 2], s = G[17 + w * 2];
        const int M = 8 >> w;
#pragma unroll
        for (int i = 0; i < 16; ++i) {
            if (!(i & M)) {
                const int j = i | M;
                const h2 ar = zr[i], ai = zi[i];
                const h2 br = zr[j], bi = zi[j];
                zr[i] = ef(c, ar,   s * bi);
                zi[i] = ef(c, ai, -(s * br));
                zr[j] = ef(c, br,   s * ai);
                zi[j] = ef(c, bi, -(s * ar));
            }
        }
    }

    // Layer-1 CNOT ring
    cnot<8, 4>(zr, zi);
    cnot<4, 2>(zr, zi);
    cnot<2, 1>(zr, zi);
    cnot<1, 8>(zr, zi);

    // Probabilities (packed), then f32 ev trees per element.
    float pA[16], pB[16];
#pragma unroll
    for (int i = 0; i < 16; ++i) {
        const h2 p = ef(zr[i], zr[i], zi[i] * zi[i]);
        pA[i] = (float)p.x;
        pB[i] = (float)p.y;
    }

#pragma unroll
    for (int e = 0; e < 2; ++e) {
        const float* p = (e == 0) ? pA : pB;
        float d0[8], s1[8];
#pragma unroll
        for (int k = 0; k < 8; ++k) {
            d0[k] = p[2 * k] - p[2 * k + 1];
            s1[k] = p[2 * k] + p[2 * k + 1];
        }
        const float e3 = ((d0[0] + d0[1]) + (d0[2] + d0[3])) + ((d0[4] + d0[5]) + (d0[6] + d0[7]));
        const float e2 = ((s1[0] - s1[1]) + (s1[2] - s1[3])) + ((s1[4] - s1[5]) + (s1[6] - s1[7]));
        float s2[4];
#pragma unroll
        for (int k = 0; k < 4; ++k) s2[k] = s1[2 * k] + s1[2 * k + 1];
        const float e1 = (s2[0] - s2[1]) + (s2[2] - s2[3]);
        const float e0 = (s2[0] + s2[1]) - (s2[2] + s2[3]);
        const int idx = (e == 0) ? i0 : i1;
        if (idx < batch)
            reinterpret_cast<float4*>(out)[idx] = make_float4(e0, e1, e2, e3);
    }
}

extern "C" void kernel_launch(void* const* d_in, const int* in_sizes, int n_in,
                              void* d_out, int out_size, void* d_ws, size_t ws_size,
                              hipStream_t stream) {
    const float* x = (const float*)d_in[0];        // (B, 4) float32
    const float* params = (const float*)d_in[1];   // (2, 4, 2) float32
    float* out = (float*)d_out;                    // (B, 4) float32
    unsigned int* g = (unsigned int*)d_ws;         // 56 half-replicated constants
    const int batch = in_sizes[0] / NUM_WIRES;

    gate_prep<<<1, 64, 0, stream>>>(params, g);
    const int blocks = (batch + 511) / 512;
    qsim_kernel<<<blocks, 256, 0, stream>>>(x, g, out, batch);
}